// Round 14
// baseline (1264.987 us; speedup 1.0000x reference)
//
#include <hip/hip_runtime.h>
#include <hip/hip_bf16.h>

#define HW 4096
#define NB 4

// ---- 1x1 conv NCHW f32 -> f32 ----
__global__ __launch_bounds__(256) void k_c1x1(const float* __restrict__ in, const float* __restrict__ w,
                                              const float* __restrict__ bias, float* __restrict__ out,
                                              int IC, int OC){
  int bo = blockIdx.x;
  int b  = bo / OC, oc = bo % OC;
  int p  = blockIdx.y*256 + threadIdx.x;
  const float* ib = in + (size_t)b*IC*HW + p;
  const float* wr = w + (size_t)oc*IC;
  float acc = bias[oc];
  for (int ic = 0; ic < IC; ++ic)
    acc += ib[(size_t)ic*HW] * wr[ic];
  out[(size_t)bo*HW + p] = acc;
}

// ---- depthwise 3x3 pad1, f32 -> f32 ----
__global__ __launch_bounds__(256) void k_dw3(const float* __restrict__ in, const float* __restrict__ w,
                                             const float* __restrict__ bias, float* __restrict__ out, int OC){
  int bo = blockIdx.x;
  int oc = bo % OC;
  int p  = blockIdx.y*256 + threadIdx.x;
  int y = p >> 6, x = p & 63;
  const float* ib = in + (size_t)bo*HW;
  float acc = bias[oc];
  for (int dy = 0; dy < 3; ++dy){
    int yy = y + dy - 1;
    if (yy < 0 || yy > 63) continue;
    for (int dx = 0; dx < 3; ++dx){
      int xx = x + dx - 1;
      if (xx < 0 || xx > 63) continue;
      acc += ib[yy*64 + xx] * w[oc*9 + dy*3 + dx];
    }
  }
  out[(size_t)bo*HW + p] = acc;
}

// ---- deformable depthwise conv, NCHW f32 (identity tap order, matching reference) ----
template<int K, int PAD, int DIL>
__global__ __launch_bounds__(256) void k_deform(const float* __restrict__ x, const float* __restrict__ off,
                                                const float* __restrict__ dw, float* __restrict__ out){
  constexpr int K2 = K*K;
  int bc = blockIdx.x;
  int b  = bc >> 8;
  int c  = bc & 255;
  int p  = blockIdx.y*256 + threadIdx.x;
  int yi = p >> 6, xi = p & 63;
  const float* xb  = x   + (size_t)bc*HW;
  const float* ob  = off + (size_t)b*2*K2*HW + p;
  const float* dwc = dw + c*K2;
  float acc = 0.f;
  for (int tt = 0; tt < K2; ++tt){
    float dy = ob[(size_t)(2*tt)*HW];
    float dx = ob[(size_t)(2*tt+1)*HW];
    float py = (float)(yi + (tt/K)*DIL - PAD) + dy;
    float px = (float)(xi + (tt%K)*DIL - PAD) + dx;
    float fy = floorf(py), fx = floorf(px);
    float ty = py - fy, tx = px - fx;
    int iy = (int)fy, ix = (int)fx;
    bool y0 = (unsigned)iy     < 64u, y1 = (unsigned)(iy+1) < 64u;
    bool x0 = (unsigned)ix     < 64u, x1 = (unsigned)(ix+1) < 64u;
    const float* bp = xb + iy*64 + ix;
    float v = 0.f;
    if (y0 && x0) v += (1.f-ty)*(1.f-tx) * bp[0];
    if (y0 && x1) v += (1.f-ty)*tx       * bp[1];
    if (y1 && x0) v += ty*(1.f-tx)       * bp[64];
    if (y1 && x1) v += ty*tx             * bp[65];
    acc += v * dwc[tt];
  }
  out[(size_t)bc*HW + p] = acc;
}

// ---- final 1x1 + x-multiply, f32, in-place tile-safe over d_out ----
// block = (b, 32-pixel tile); reads attn (=d_out) for all 256 ch of its own tile
// BEFORE writing the same region. grid NB*128, block 256 (thread = oc).
__global__ __launch_bounds__(256) void k_final(const float* __restrict__ attn, const float* __restrict__ w1,
                                               const float* __restrict__ b1, const float* __restrict__ x,
                                               float* __restrict__ out){
  __shared__ float at[256][33];   // [ic][px] padded
  __shared__ float wt[256][17];   // [oc][ic-chunk 16]
  int t   = threadIdx.x;
  int blk = blockIdx.x;
  int b   = blk >> 7;
  int p0  = (blk & 127) * 32;
  for (int i = 0; i < 32; ++i)
    at[t][i] = attn[((size_t)b*256 + t)*HW + p0 + i];
  float acc[32];
  float bv = b1[t];
  for (int i = 0; i < 32; ++i) acc[i] = bv;
  for (int c0 = 0; c0 < 256; c0 += 16){
    __syncthreads();               // at visible (1st) / wt consumed (later)
    for (int k = 0; k < 16; ++k){
      int idx = k*256 + t;
      wt[idx >> 4][idx & 15] = w1[(idx >> 4)*256 + c0 + (idx & 15)];
    }
    __syncthreads();
    for (int j = 0; j < 16; ++j){
      float wv = wt[t][j];
      const float* ar = &at[c0 + j][0];
      for (int i = 0; i < 32; ++i)
        acc[i] += wv * ar[i];
    }
  }
  size_t gi = ((size_t)b*256 + t)*HW + p0;
  for (int i = 0; i < 32; ++i)
    out[gi + i] = acc[i] * x[gi + i];
}

extern "C" void kernel_launch(void* const* d_in, const int* in_sizes, int n_in,
                              void* d_out, int out_size, void* d_ws, size_t ws_size,
                              hipStream_t stream){
  const float* x   = (const float*)d_in[0];
  const float* aw0 = (const float*)d_in[1];
  const float* ab0 = (const float*)d_in[2];
  const float* ow0 = (const float*)d_in[3];
  const float* ob0 = (const float*)d_in[4];
  const float* dw0 = (const float*)d_in[5];
  const float* aw1 = (const float*)d_in[6];
  const float* ab1 = (const float*)d_in[7];
  const float* ow1 = (const float*)d_in[8];
  const float* ob1 = (const float*)d_in[9];
  const float* dw1 = (const float*)d_in[10];
  const float* w1  = (const float*)d_in[11];
  const float* b1  = (const float*)d_in[12];
  float* O = (float*)d_out;                       // OUTPUT IS FLOAT32

  // ws: A0 f32 @0 (16,777,216) | XC f32 @16,777,216 (6,422,528) | OF f32 @23,199,744 (6,422,528)
  // total 29,622,272 (proven available). A1 f32 lives in d_out (16,777,216 B).
  char* ws = (char*)d_ws;
  float* A0 = (float*)(ws);
  float* XC = (float*)(ws + 16777216);
  float* OF = (float*)(ws + 23199744);
  float* A1 = O;

  // block 0 (K=5, pad 2, dil 1)
  k_c1x1<<<dim3(NB*50, 16), 256, 0, stream>>>(x, aw0, ab0, XC, 256, 50);
  k_dw3<<<dim3(NB*50, 16), 256, 0, stream>>>(XC, ow0, ob0, OF, 50);
  k_deform<5,2,1><<<dim3(NB*256, 16), 256, 0, stream>>>(x, OF, dw0, A0);
  // block 1 (K=7, pad 9, dil 3)
  k_c1x1<<<dim3(NB*98, 16), 256, 0, stream>>>(A0, aw1, ab1, XC, 256, 98);
  k_dw3<<<dim3(NB*98, 16), 256, 0, stream>>>(XC, ow1, ob1, OF, 98);
  k_deform<7,9,3><<<dim3(NB*256, 16), 256, 0, stream>>>(A0, OF, dw1, A1);
  // final 1x1 + x-multiply, in-place over d_out
  k_final<<<NB*128, 256, 0, stream>>>(A1, w1, b1, x, O);
}

// Round 15
// 1215.878 us; speedup vs baseline: 1.0404x; 1.0404x over previous
//
#include <hip/hip_runtime.h>
#include <hip/hip_bf16.h>

#define HW 4096
#define NB 4

// ---- 1x1 conv NCHW f32 -> f32 ----
__global__ __launch_bounds__(256) void k_c1x1(const float* __restrict__ in, const float* __restrict__ w,
                                              const float* __restrict__ bias, float* __restrict__ out,
                                              int IC, int OC){
  int bo = blockIdx.x;
  int b  = bo / OC, oc = bo % OC;
  int p  = blockIdx.y*256 + threadIdx.x;
  const float* ib = in + (size_t)b*IC*HW + p;
  const float* wr = w + (size_t)oc*IC;
  float acc = bias[oc];
  for (int ic = 0; ic < IC; ++ic)
    acc += ib[(size_t)ic*HW] * wr[ic];
  out[(size_t)bo*HW + p] = acc;
}

// ---- depthwise 3x3 pad1, f32 -> f32 ----
__global__ __launch_bounds__(256) void k_dw3(const float* __restrict__ in, const float* __restrict__ w,
                                             const float* __restrict__ bias, float* __restrict__ out, int OC){
  int bo = blockIdx.x;
  int oc = bo % OC;
  int p  = blockIdx.y*256 + threadIdx.x;
  int y = p >> 6, x = p & 63;
  const float* ib = in + (size_t)bo*HW;
  float acc = bias[oc];
  #pragma unroll
  for (int dy = 0; dy < 3; ++dy){
    int yy = y + dy - 1;
    if (yy < 0 || yy > 63) continue;
    #pragma unroll
    for (int dx = 0; dx < 3; ++dx){
      int xx = x + dx - 1;
      if (xx < 0 || xx > 63) continue;
      acc += ib[yy*64 + xx] * w[oc*9 + dy*3 + dx];
    }
  }
  out[(size_t)bo*HW + p] = acc;
}

// ---- deformable depthwise conv, NCHW f32 — ILP-optimized ----
// branchless corners (clamped addresses + masked weights) + tap-loop unroll
template<int K, int PAD, int DIL, int UNROLL>
__global__ __launch_bounds__(256) void k_deform(const float* __restrict__ x, const float* __restrict__ off,
                                                const float* __restrict__ dw, float* __restrict__ out){
  constexpr int K2 = K*K;
  int bc = blockIdx.x;
  int b  = bc >> 8;
  int c  = bc & 255;
  int p  = blockIdx.y*256 + threadIdx.x;
  int yi = p >> 6, xi = p & 63;
  const float* xb  = x   + (size_t)bc*HW;
  const float* ob  = off + (size_t)b*2*K2*HW + p;
  const float* dwc = dw + c*K2;
  float acc = 0.f;
  #pragma unroll UNROLL
  for (int tt = 0; tt < K2; ++tt){
    float dy = ob[(size_t)(2*tt)*HW];
    float dx = ob[(size_t)(2*tt+1)*HW];
    float py = (float)(yi + (tt/K)*DIL - PAD) + dy;
    float px = (float)(xi + (tt%K)*DIL - PAD) + dx;
    float fy = floorf(py), fx = floorf(px);
    float ty = py - fy, tx = px - fx;
    int iy = (int)fy, ix = (int)fx;
    // validity masks
    float my0 = ((unsigned)iy     < 64u) ? 1.f : 0.f;
    float my1 = ((unsigned)(iy+1) < 64u) ? 1.f : 0.f;
    float mx0 = ((unsigned)ix     < 64u) ? 1.f : 0.f;
    float mx1 = ((unsigned)(ix+1) < 64u) ? 1.f : 0.f;
    // clamped in-plane addresses (reads are always safe; masked weights kill invalid)
    int cy0 = min(max(iy,     0), 63);
    int cy1 = min(max(iy + 1, 0), 63);
    int cx0 = min(max(ix,     0), 63);
    int cx1 = min(max(ix + 1, 0), 63);
    float w00 = (1.f-ty)*(1.f-tx) * (my0*mx0);
    float w01 = (1.f-ty)*tx       * (my0*mx1);
    float w10 = ty*(1.f-tx)       * (my1*mx0);
    float w11 = ty*tx             * (my1*mx1);
    float v00 = xb[cy0*64 + cx0];
    float v01 = xb[cy0*64 + cx1];
    float v10 = xb[cy1*64 + cx0];
    float v11 = xb[cy1*64 + cx1];
    float wk = dwc[tt];
    acc += (w00*v00 + w01*v01 + w10*v10 + w11*v11) * wk;
  }
  out[(size_t)bc*HW + p] = acc;
}

// ---- final 1x1 + x-multiply, f32, in-place tile-safe over d_out ----
__global__ __launch_bounds__(256) void k_final(const float* __restrict__ attn, const float* __restrict__ w1,
                                               const float* __restrict__ b1, const float* __restrict__ x,
                                               float* __restrict__ out){
  __shared__ float at[256][33];
  __shared__ float wt[256][17];
  int t   = threadIdx.x;
  int blk = blockIdx.x;
  int b   = blk >> 7;
  int p0  = (blk & 127) * 32;
  for (int i = 0; i < 32; ++i)
    at[t][i] = attn[((size_t)b*256 + t)*HW + p0 + i];
  float acc[32];
  float bv = b1[t];
  for (int i = 0; i < 32; ++i) acc[i] = bv;
  for (int c0 = 0; c0 < 256; c0 += 16){
    __syncthreads();
    for (int k = 0; k < 16; ++k){
      int idx = k*256 + t;
      wt[idx >> 4][idx & 15] = w1[(idx >> 4)*256 + c0 + (idx & 15)];
    }
    __syncthreads();
    for (int j = 0; j < 16; ++j){
      float wv = wt[t][j];
      const float* ar = &at[c0 + j][0];
      for (int i = 0; i < 32; ++i)
        acc[i] += wv * ar[i];
    }
  }
  size_t gi = ((size_t)b*256 + t)*HW + p0;
  for (int i = 0; i < 32; ++i)
    out[gi + i] = acc[i] * x[gi + i];
}

extern "C" void kernel_launch(void* const* d_in, const int* in_sizes, int n_in,
                              void* d_out, int out_size, void* d_ws, size_t ws_size,
                              hipStream_t stream){
  const float* x   = (const float*)d_in[0];
  const float* aw0 = (const float*)d_in[1];
  const float* ab0 = (const float*)d_in[2];
  const float* ow0 = (const float*)d_in[3];
  const float* ob0 = (const float*)d_in[4];
  const float* dw0 = (const float*)d_in[5];
  const float* aw1 = (const float*)d_in[6];
  const float* ab1 = (const float*)d_in[7];
  const float* ow1 = (const float*)d_in[8];
  const float* ob1 = (const float*)d_in[9];
  const float* dw1 = (const float*)d_in[10];
  const float* w1  = (const float*)d_in[11];
  const float* b1  = (const float*)d_in[12];
  float* O = (float*)d_out;

  // ws: A0 f32 @0 (16,777,216) | XC f32 @16,777,216 (6,422,528) | OF f32 @23,199,744 (6,422,528)
  char* ws = (char*)d_ws;
  float* A0 = (float*)(ws);
  float* XC = (float*)(ws + 16777216);
  float* OF = (float*)(ws + 23199744);
  float* A1 = O;

  // block 0 (K=5, pad 2, dil 1)
  k_c1x1<<<dim3(NB*50, 16), 256, 0, stream>>>(x, aw0, ab0, XC, 256, 50);
  k_dw3<<<dim3(NB*50, 16), 256, 0, stream>>>(XC, ow0, ob0, OF, 50);
  k_deform<5,2,1,5><<<dim3(NB*256, 16), 256, 0, stream>>>(x, OF, dw0, A0);
  // block 1 (K=7, pad 9, dil 3)
  k_c1x1<<<dim3(NB*98, 16), 256, 0, stream>>>(A0, aw1, ab1, XC, 256, 98);
  k_dw3<<<dim3(NB*98, 16), 256, 0, stream>>>(XC, ow1, ob1, OF, 98);
  k_deform<7,9,3,7><<<dim3(NB*256, 16), 256, 0, stream>>>(A0, OF, dw1, A1);
  // final 1x1 + x-multiply, in-place over d_out
  k_final<<<NB*128, 256, 0, stream>>>(A1, w1, b1, x, O);
}

// Round 16
// 1087.389 us; speedup vs baseline: 1.1633x; 1.1182x over previous
//
#include <hip/hip_runtime.h>
#include <hip/hip_bf16.h>
#include <hip/hip_fp16.h>

typedef __hip_bfloat16 bf16;
typedef unsigned int   u32;
typedef unsigned short u16;

#define HW 4096
#define NB 4

__device__ __forceinline__ float ldx(const float* p){ return *p; }
__device__ __forceinline__ float ldx(const bf16*  p){ return __bfloat162float(*p); }

// ---- 1x1 conv NCHW -> f32 ----
template<typename Tin>
__global__ __launch_bounds__(256) void k_c1x1(const Tin* __restrict__ in, const float* __restrict__ w,
                                              const float* __restrict__ bias, float* __restrict__ out,
                                              int IC, int OC){
  int bo = blockIdx.x;
  int b  = bo / OC, oc = bo % OC;
  int p  = blockIdx.y*256 + threadIdx.x;
  const Tin* ib = in + (size_t)b*IC*HW + p;
  const float* wr = w + (size_t)oc*IC;
  float acc = bias[oc];
  for (int ic = 0; ic < IC; ++ic)
    acc += ldx(ib + (size_t)ic*HW) * wr[ic];
  out[(size_t)bo*HW + p] = acc;
}

// ---- depthwise 3x3 pad1, f32 -> f32 ----
__global__ __launch_bounds__(256) void k_dw3(const float* __restrict__ in, const float* __restrict__ w,
                                             const float* __restrict__ bias, float* __restrict__ out, int OC){
  int bo = blockIdx.x;
  int oc = bo % OC;
  int p  = blockIdx.y*256 + threadIdx.x;
  int y = p >> 6, x = p & 63;
  const float* ib = in + (size_t)bo*HW;
  float acc = bias[oc];
  #pragma unroll
  for (int dy = 0; dy < 3; ++dy){
    int yy = y + dy - 1;
    if (yy < 0 || yy > 63) continue;
    #pragma unroll
    for (int dx = 0; dx < 3; ++dx){
      int xx = x + dx - 1;
      if (xx < 0 || xx > 63) continue;
      acc += ib[yy*64 + xx] * w[oc*9 + dy*3 + dx];
    }
  }
  out[(size_t)bo*HW + p] = acc;
}

// ---- precompute bilinear tables: per (b,tap,pixel) -> 4 f16 slot-weights + u16 base ----
// base = clamp(iy,0,62)*64 + clamp(ix,0,62); weights slot-mapped so corner reads
// base,+1,+64,+65 are always in-plane and invalid corners get weight 0.
template<int K, int PAD, int DIL>
__global__ __launch_bounds__(256) void k_precomp(const float* __restrict__ off,
                                                 uint2* __restrict__ pw, u16* __restrict__ pa){
  constexpr int K2 = K*K;
  int bt = blockIdx.x;                 // b*K2 + tt
  int b  = bt / K2, tt = bt % K2;
  int p  = blockIdx.y*256 + threadIdx.x;
  int yi = p >> 6, xi = p & 63;
  const float* ob = off + ((size_t)(b*2*K2) + 2*tt)*HW + p;
  float dy = ob[0];
  float dx = ob[HW];
  float py = (float)(yi + (tt/K)*DIL - PAD) + dy;
  float px = (float)(xi + (tt%K)*DIL - PAD) + dx;
  float fy = floorf(py), fx = floorf(px);
  float ty = py - fy, tx = px - fx;
  int iy = (int)fy, ix = (int)fx;
  int sy = min(max(iy, 0), 62);
  int sx = min(max(ix, 0), 62);
  float wy0 = (sy   == iy) ? (1.f-ty) : ((sy   == iy+1) ? ty : 0.f);
  float wy1 = (sy+1 == iy) ? (1.f-ty) : ((sy+1 == iy+1) ? ty : 0.f);
  float wx0 = (sx   == ix) ? (1.f-tx) : ((sx   == ix+1) ? tx : 0.f);
  float wx1 = (sx+1 == ix) ? (1.f-tx) : ((sx+1 == ix+1) ? tx : 0.f);
  u32 lo = (u32)__half_as_ushort(__float2half(wy0*wx0))
         | ((u32)__half_as_ushort(__float2half(wy0*wx1)) << 16);
  u32 hi = (u32)__half_as_ushort(__float2half(wy1*wx0))
         | ((u32)__half_as_ushort(__float2half(wy1*wx1)) << 16);
  size_t idx = (size_t)bt*HW + p;
  pw[idx] = make_uint2(lo, hi);
  pa[idx] = (u16)(sy*64 + sx);
}

// ---- deformable depthwise conv using precomputed tables ----
template<int K2, typename Tx, typename Tout, int UNR>
__global__ __launch_bounds__(256) void k_deform(const Tx* __restrict__ x, const uint2* __restrict__ pw,
                                                const u16* __restrict__ pa, const float* __restrict__ dw,
                                                Tout* __restrict__ out){
  int bc = blockIdx.x;                 // b*256 + c
  int b  = bc >> 8, c = bc & 255;
  int p  = blockIdx.y*256 + threadIdx.x;
  const Tx* xb = x + (size_t)bc*HW;
  const float* dwc = dw + c*K2;
  size_t bi = (size_t)(b*K2)*HW + p;
  float acc = 0.f;
  #pragma unroll UNR
  for (int tt = 0; tt < K2; ++tt){
    uint2 wv = pw[bi + (size_t)tt*HW];
    int   a  = pa[bi + (size_t)tt*HW];
    float W00 = __half2float(__ushort_as_half((u16)(wv.x & 0xffffu)));
    float W01 = __half2float(__ushort_as_half((u16)(wv.x >> 16)));
    float W10 = __half2float(__ushort_as_half((u16)(wv.y & 0xffffu)));
    float W11 = __half2float(__ushort_as_half((u16)(wv.y >> 16)));
    float v00 = ldx(xb + a);
    float v01 = ldx(xb + a + 1);
    float v10 = ldx(xb + a + 64);
    float v11 = ldx(xb + a + 65);
    acc += dwc[tt] * (W00*v00 + W01*v01 + W10*v10 + W11*v11);
  }
  if constexpr (sizeof(Tout) == 2) out[(size_t)bc*HW + p] = __float2bfloat16(acc);
  else                             out[(size_t)bc*HW + p] = acc;
}

// ---- final 1x1 + x-multiply, f32, in-place tile-safe over d_out ----
__global__ __launch_bounds__(256) void k_final(const float* __restrict__ attn, const float* __restrict__ w1,
                                               const float* __restrict__ b1, const float* __restrict__ x,
                                               float* __restrict__ out){
  __shared__ float at[256][33];
  __shared__ float wt[256][17];
  int t   = threadIdx.x;
  int blk = blockIdx.x;
  int b   = blk >> 7;
  int p0  = (blk & 127) * 32;
  for (int i = 0; i < 32; ++i)
    at[t][i] = attn[((size_t)b*256 + t)*HW + p0 + i];
  float acc[32];
  float bv = b1[t];
  for (int i = 0; i < 32; ++i) acc[i] = bv;
  for (int c0 = 0; c0 < 256; c0 += 16){
    __syncthreads();
    for (int k = 0; k < 16; ++k){
      int idx = k*256 + t;
      wt[idx >> 4][idx & 15] = w1[(idx >> 4)*256 + c0 + (idx & 15)];
    }
    __syncthreads();
    for (int j = 0; j < 16; ++j){
      float wv = wt[t][j];
      const float* ar = &at[c0 + j][0];
      for (int i = 0; i < 32; ++i)
        acc[i] += wv * ar[i];
    }
  }
  size_t gi = ((size_t)b*256 + t)*HW + p0;
  for (int i = 0; i < 32; ++i)
    out[gi + i] = acc[i] * x[gi + i];
}

extern "C" void kernel_launch(void* const* d_in, const int* in_sizes, int n_in,
                              void* d_out, int out_size, void* d_ws, size_t ws_size,
                              hipStream_t stream){
  const float* x   = (const float*)d_in[0];
  const float* aw0 = (const float*)d_in[1];
  const float* ab0 = (const float*)d_in[2];
  const float* ow0 = (const float*)d_in[3];
  const float* ob0 = (const float*)d_in[4];
  const float* dw0 = (const float*)d_in[5];
  const float* aw1 = (const float*)d_in[6];
  const float* ab1 = (const float*)d_in[7];
  const float* ow1 = (const float*)d_in[8];
  const float* ob1 = (const float*)d_in[9];
  const float* dw1 = (const float*)d_in[10];
  const float* w1  = (const float*)d_in[11];
  const float* b1  = (const float*)d_in[12];
  float* O = (float*)d_out;

  // ws layout (peak 29,261,824 B <= proven 29.6 MB):
  //   A0  bf16 @0          (8,388,608)
  //   P1w 8B   @8,388,608  (6,422,528)   [P0w 3,276,800 + P0a 819,200 overlay this slot in block0]
  //   XC  f32  @14,811,136 (6,422,528)
  //   OF  f32  @21,233,664 (6,422,528)
  //   P1a u16  @27,656,192 (1,605,632)
  char* ws = (char*)d_ws;
  bf16*  A0  = (bf16*) (ws);
  uint2* P1w = (uint2*)(ws + 8388608);
  uint2* P0w = (uint2*)(ws + 8388608);
  u16*   P0a = (u16*)  (ws + 8388608 + 3276800);
  float* XC  = (float*)(ws + 14811136);
  float* OF  = (float*)(ws + 21233664);
  u16*   P1a = (u16*)  (ws + 27656192);
  float* A1  = O;

  // block 0 (K=5, pad 2, dil 1)
  k_c1x1<float><<<dim3(NB*50, 16), 256, 0, stream>>>(x, aw0, ab0, XC, 256, 50);
  k_dw3<<<dim3(NB*50, 16), 256, 0, stream>>>(XC, ow0, ob0, OF, 50);
  k_precomp<5,2,1><<<dim3(NB*25, 16), 256, 0, stream>>>(OF, P0w, P0a);
  k_deform<25, float, bf16, 5><<<dim3(NB*256, 16), 256, 0, stream>>>(x, P0w, P0a, dw0, A0);
  // block 1 (K=7, pad 9, dil 3)
  k_c1x1<bf16><<<dim3(NB*98, 16), 256, 0, stream>>>(A0, aw1, ab1, XC, 256, 98);
  k_dw3<<<dim3(NB*98, 16), 256, 0, stream>>>(XC, ow1, ob1, OF, 98);
  k_precomp<7,9,3><<<dim3(NB*49, 16), 256, 0, stream>>>(OF, P1w, P1a);
  k_deform<49, bf16, float, 7><<<dim3(NB*256, 16), 256, 0, stream>>>(A0, P1w, P1a, dw1, A1);
  // final 1x1 + x-multiply, in-place over d_out
  k_final<<<NB*128, 256, 0, stream>>>(A1, w1, b1, x, O);
}

// Round 17
// 609.271 us; speedup vs baseline: 2.0762x; 1.7847x over previous
//
#include <hip/hip_runtime.h>
#include <hip/hip_bf16.h>
#include <hip/hip_fp16.h>

typedef __hip_bfloat16 bf16;
typedef unsigned int   u32;
typedef unsigned short u16;

#define HW 4096
#define NB 4

__device__ __forceinline__ float ldx(const float* p){ return *p; }
__device__ __forceinline__ float ldx(const bf16*  p){ return __bfloat162float(*p); }
__device__ __forceinline__ float blo(u32 v){ return __uint_as_float(v << 16); }
__device__ __forceinline__ float bhi(u32 v){ return __uint_as_float(v & 0xffff0000u); }
__device__ __forceinline__ u32 pack2(float a, float b){
  union { bf16 h; u16 u; } ua, ub;
  ua.h = __float2bfloat16(a); ub.h = __float2bfloat16(b);
  return (u32)ua.u | ((u32)ub.u << 16);
}

// ---- transpose dw[c][K2] -> dwT[tt][256] ----
__global__ __launch_bounds__(256) void k_dwT(const float* __restrict__ dw, float* __restrict__ dwT, int K2){
  int tt = blockIdx.x;
  dwT[tt*256 + threadIdx.x] = dw[threadIdx.x*K2 + tt];
}

// ---- transpose x NCHW f32 -> xh NHWC bf16 ----
__global__ __launch_bounds__(256) void k_transpose(const float* __restrict__ x, bf16* __restrict__ xh){
  __shared__ float tile[64][65];
  int t = threadIdx.x, blk = blockIdx.x;
  int ct = blk & 3, pt = (blk >> 2) & 63, b = blk >> 8;
  int lp = t & 63, l4 = t >> 6;
  #pragma unroll
  for (int i = 0; i < 16; ++i){
    int cl = l4 + 4*i;
    tile[cl][lp] = x[((size_t)(b*256 + ct*64 + cl))*HW + pt*64 + lp];
  }
  __syncthreads();
  #pragma unroll
  for (int i = 0; i < 16; ++i){
    int pl = l4 + 4*i;
    xh[((size_t)b*HW + pt*64 + pl)*256 + ct*64 + lp] = __float2bfloat16(tile[lp][pl]);
  }
}

// ---- 1x1 conv NCHW -> f32 (proven) ----
template<typename Tin>
__global__ __launch_bounds__(256) void k_c1x1(const Tin* __restrict__ in, const float* __restrict__ w,
                                              const float* __restrict__ bias, float* __restrict__ out,
                                              int IC, int OC){
  int bo = blockIdx.x;
  int b  = bo / OC, oc = bo % OC;
  int p  = blockIdx.y*256 + threadIdx.x;
  const Tin* ib = in + (size_t)b*IC*HW + p;
  const float* wr = w + (size_t)oc*IC;
  float acc = bias[oc];
  for (int ic = 0; ic < IC; ++ic)
    acc += ldx(ib + (size_t)ic*HW) * wr[ic];
  out[(size_t)bo*HW + p] = acc;
}

// ---- depthwise 3x3 pad1, f32 -> f32 (proven) ----
__global__ __launch_bounds__(256) void k_dw3(const float* __restrict__ in, const float* __restrict__ w,
                                             const float* __restrict__ bias, float* __restrict__ out, int OC){
  int bo = blockIdx.x;
  int oc = bo % OC;
  int p  = blockIdx.y*256 + threadIdx.x;
  int y = p >> 6, x = p & 63;
  const float* ib = in + (size_t)bo*HW;
  float acc = bias[oc];
  #pragma unroll
  for (int dy = 0; dy < 3; ++dy){
    int yy = y + dy - 1;
    if (yy < 0 || yy > 63) continue;
    #pragma unroll
    for (int dx = 0; dx < 3; ++dx){
      int xx = x + dx - 1;
      if (xx < 0 || xx > 63) continue;
      acc += ib[yy*64 + xx] * w[oc*9 + dy*3 + dx];
    }
  }
  out[(size_t)bo*HW + p] = acc;
}

// ---- precompute bilinear tables (proven): 4 f16 slot-weights + u16 clamped base ----
template<int K, int PAD, int DIL>
__global__ __launch_bounds__(256) void k_precomp(const float* __restrict__ off,
                                                 uint2* __restrict__ pw, u16* __restrict__ pa){
  constexpr int K2 = K*K;
  int bt = blockIdx.x;                 // b*K2 + tt
  int b  = bt / K2, tt = bt % K2;
  int p  = blockIdx.y*256 + threadIdx.x;
  int yi = p >> 6, xi = p & 63;
  const float* ob = off + ((size_t)(b*2*K2) + 2*tt)*HW + p;
  float dy = ob[0];
  float dx = ob[HW];
  float py = (float)(yi + (tt/K)*DIL - PAD) + dy;
  float px = (float)(xi + (tt%K)*DIL - PAD) + dx;
  float fy = floorf(py), fx = floorf(px);
  float ty = py - fy, tx = px - fx;
  int iy = (int)fy, ix = (int)fx;
  int sy = min(max(iy, 0), 62);
  int sx = min(max(ix, 0), 62);
  float wy0 = (sy   == iy) ? (1.f-ty) : ((sy   == iy+1) ? ty : 0.f);
  float wy1 = (sy+1 == iy) ? (1.f-ty) : ((sy+1 == iy+1) ? ty : 0.f);
  float wx0 = (sx   == ix) ? (1.f-tx) : ((sx   == ix+1) ? tx : 0.f);
  float wx1 = (sx+1 == ix) ? (1.f-tx) : ((sx+1 == ix+1) ? tx : 0.f);
  u32 lo = (u32)__half_as_ushort(__float2half(wy0*wx0))
         | ((u32)__half_as_ushort(__float2half(wy0*wx1)) << 16);
  u32 hi = (u32)__half_as_ushort(__float2half(wy1*wx0))
         | ((u32)__half_as_ushort(__float2half(wy1*wx1)) << 16);
  size_t idx = (size_t)bt*HW + p;
  pw[idx] = make_uint2(lo, hi);
  pa[idx] = (u16)(sy*64 + sx);
}

// ---- NHWC deformable depthwise: thread = (pixel, channel-group of 8) ----
// block: 256 thr = 8 px x 32 cg. Corner loads: uint4 = 8 bf16, coalesced across cg.
template<int K2, bool WNCHW>
__global__ __launch_bounds__(256) void k_deform_nhwc(
    const bf16* __restrict__ xh, const uint2* __restrict__ pw, const u16* __restrict__ pa,
    const float* __restrict__ dwT, bf16* __restrict__ oh, bf16* __restrict__ onchw){
  __shared__ uint2 lw[K2][8];
  __shared__ u16   la[K2][8];
  __shared__ float trf[WNCHW ? 256 : 1][8];
  int t  = threadIdx.x;
  int cg = t & 31;
  int pl = t >> 5;
  int blk = blockIdx.x;        // b*512 + ptile
  int b   = blk >> 9;
  int p0  = (blk & 511) * 8;
  for (int e = t; e < 8*K2; e += 256){
    int tt = e >> 3, pxl = e & 7;
    size_t gi = ((size_t)(b*K2 + tt))*HW + p0 + pxl;
    lw[tt][pxl] = pw[gi];
    la[tt][pxl] = pa[gi];
  }
  __syncthreads();
  const bf16* xb = xh + (size_t)b*HW*256;
  float acc[8];
  #pragma unroll
  for (int j = 0; j < 8; ++j) acc[j] = 0.f;
  for (int tt = 0; tt < K2; ++tt){
    uint2 wv = lw[tt][pl];
    int   a  = la[tt][pl];
    float W00 = __half2float(__ushort_as_half((u16)(wv.x & 0xffffu)));
    float W01 = __half2float(__ushort_as_half((u16)(wv.x >> 16)));
    float W10 = __half2float(__ushort_as_half((u16)(wv.y & 0xffffu)));
    float W11 = __half2float(__ushort_as_half((u16)(wv.y >> 16)));
    const bf16* base = xb + (size_t)a*256 + cg*8;
    uint4 r00 = *(const uint4*)(base);
    uint4 r01 = *(const uint4*)(base + 256);
    uint4 r10 = *(const uint4*)(base + 64*256);
    uint4 r11 = *(const uint4*)(base + 65*256);
    float4 dwa = *(const float4*)(dwT + tt*256 + cg*8);
    float4 dwb = *(const float4*)(dwT + tt*256 + cg*8 + 4);
    const u32 q00[4] = {r00.x, r00.y, r00.z, r00.w};
    const u32 q01[4] = {r01.x, r01.y, r01.z, r01.w};
    const u32 q10[4] = {r10.x, r10.y, r10.z, r10.w};
    const u32 q11[4] = {r11.x, r11.y, r11.z, r11.w};
    const float dwv[8] = {dwa.x, dwa.y, dwa.z, dwa.w, dwb.x, dwb.y, dwb.z, dwb.w};
    #pragma unroll
    for (int q = 0; q < 4; ++q){
      float sl = W00*blo(q00[q]) + W01*blo(q01[q]) + W10*blo(q10[q]) + W11*blo(q11[q]);
      float sh = W00*bhi(q00[q]) + W01*bhi(q01[q]) + W10*bhi(q10[q]) + W11*bhi(q11[q]);
      acc[2*q]   += dwv[2*q]   * sl;
      acc[2*q+1] += dwv[2*q+1] * sh;
    }
  }
  // NHWC store: 8 ch bf16 = 16B
  size_t op = ((size_t)b*HW + p0 + pl)*256 + cg*8;
  uint4 ov;
  ov.x = pack2(acc[0], acc[1]); ov.y = pack2(acc[2], acc[3]);
  ov.z = pack2(acc[4], acc[5]); ov.w = pack2(acc[6], acc[7]);
  *(uint4*)(oh + op) = ov;
  if constexpr (WNCHW){
    __syncthreads();
    #pragma unroll
    for (int j = 0; j < 8; ++j) trf[cg*8 + j][pl] = acc[j];
    __syncthreads();
    // thread t = channel: write 8 px (16B) to NCHW
    uint4 oc4;
    oc4.x = pack2(trf[t][0], trf[t][1]); oc4.y = pack2(trf[t][2], trf[t][3]);
    oc4.z = pack2(trf[t][4], trf[t][5]); oc4.w = pack2(trf[t][6], trf[t][7]);
    *(uint4*)(onchw + ((size_t)(b*256 + t))*HW + p0) = oc4;
  }
}

// ---- final 1x1 + x-multiply: attn NHWC bf16 in, out NCHW f32 ----
__global__ __launch_bounds__(256) void k_final(const bf16* __restrict__ attnh, const float* __restrict__ w1,
                                               const float* __restrict__ b1, const float* __restrict__ x,
                                               float* __restrict__ out){
  __shared__ float at[256][33];
  __shared__ float wt[256][17];
  int t   = threadIdx.x;
  int blk = blockIdx.x;
  int b   = blk >> 7;
  int p0  = (blk & 127) * 32;
  for (int i = 0; i < 32; ++i)
    at[t][i] = __bfloat162float(attnh[((size_t)b*HW + p0 + i)*256 + t]);
  float acc[32];
  float bv = b1[t];
  for (int i = 0; i < 32; ++i) acc[i] = bv;
  for (int c0 = 0; c0 < 256; c0 += 16){
    __syncthreads();
    for (int k = 0; k < 16; ++k){
      int idx = k*256 + t;
      wt[idx >> 4][idx & 15] = w1[(idx >> 4)*256 + c0 + (idx & 15)];
    }
    __syncthreads();
    for (int j = 0; j < 16; ++j){
      float wv = wt[t][j];
      const float* ar = &at[c0 + j][0];
      for (int i = 0; i < 32; ++i)
        acc[i] += wv * ar[i];
    }
  }
  size_t gi = ((size_t)(b*256 + t))*HW + p0;
  for (int i = 0; i < 32; ++i)
    out[gi + i] = acc[i] * x[gi + i];
}

extern "C" void kernel_launch(void* const* d_in, const int* in_sizes, int n_in,
                              void* d_out, int out_size, void* d_ws, size_t ws_size,
                              hipStream_t stream){
  const float* x   = (const float*)d_in[0];
  const float* aw0 = (const float*)d_in[1];
  const float* ab0 = (const float*)d_in[2];
  const float* ow0 = (const float*)d_in[3];
  const float* ob0 = (const float*)d_in[4];
  const float* dw0 = (const float*)d_in[5];
  const float* aw1 = (const float*)d_in[6];
  const float* ab1 = (const float*)d_in[7];
  const float* ow1 = (const float*)d_in[8];
  const float* ob1 = (const float*)d_in[9];
  const float* dw1 = (const float*)d_in[10];
  const float* w1  = (const float*)d_in[11];
  const float* b1  = (const float*)d_in[12];
  float* O = (float*)d_out;

  // ws regions (proven ws >= 29,622,272):
  //  R0 @0        (8M): xh NHWC bf16      -> XC1 f32 (6.4M) -> P1w(6.42M)+P1a(1.6M)
  //  R1 @8M       (8M): XC0(3.2M)+OF0(3.2M) -> A0h NHWC bf16 (8M)
  //  R2 @16M      (8M): A0c NCHW bf16 (8M) -> OF1 f32 (6.42M) -> A1h NHWC bf16 (8M)
  //  R3 @24M      (5.45M): P0w(3.28M)+P0a(0.82M) | dwT0(25.6K)+dwT1(50.2K)
  const size_t MB8 = 8388608;
  char* ws = (char*)d_ws;
  bf16*  xh   = (bf16*) (ws);
  float* XC1  = (float*)(ws);
  uint2* P1w  = (uint2*)(ws);
  u16*   P1a  = (u16*)  (ws + 6422528);
  float* XC0  = (float*)(ws + MB8);
  float* OF0  = (float*)(ws + MB8 + 3276800);
  bf16*  A0h  = (bf16*) (ws + MB8);
  bf16*  A0c  = (bf16*) (ws + 2*MB8);
  float* OF1  = (float*)(ws + 2*MB8);
  bf16*  A1h  = (bf16*) (ws + 2*MB8);
  uint2* P0w  = (uint2*)(ws + 3*MB8);
  u16*   P0a  = (u16*)  (ws + 3*MB8 + 3276800);
  float* dwT0 = (float*)(ws + 3*MB8 + 4096000);
  float* dwT1 = (float*)(ws + 3*MB8 + 4198400);

  // prep (independent)
  k_dwT<<<25, 256, 0, stream>>>(dw0, dwT0, 25);
  k_dwT<<<49, 256, 0, stream>>>(dw1, dwT1, 49);
  k_transpose<<<1024, 256, 0, stream>>>(x, xh);
  // block 0 (K=5, pad 2, dil 1)
  k_c1x1<float><<<dim3(NB*50, 16), 256, 0, stream>>>(x, aw0, ab0, XC0, 256, 50);
  k_dw3<<<dim3(NB*50, 16), 256, 0, stream>>>(XC0, ow0, ob0, OF0, 50);
  k_precomp<5,2,1><<<dim3(NB*25, 16), 256, 0, stream>>>(OF0, P0w, P0a);
  k_deform_nhwc<25, true><<<NB*512, 256, 0, stream>>>(xh, P0w, P0a, dwT0, A0h, A0c);
  // block 1 (K=7, pad 9, dil 3)
  k_c1x1<bf16><<<dim3(NB*98, 16), 256, 0, stream>>>(A0c, aw1, ab1, XC1, 256, 98);
  k_dw3<<<dim3(NB*98, 16), 256, 0, stream>>>(XC1, ow1, ob1, OF1, 98);
  k_precomp<7,9,3><<<dim3(NB*49, 16), 256, 0, stream>>>(OF1, P1w, P1a);
  k_deform_nhwc<49, false><<<NB*512, 256, 0, stream>>>(A0h, P1w, P1a, dwT1, A1h, nullptr);
  // final 1x1 + x-multiply -> d_out
  k_final<<<NB*128, 256, 0, stream>>>(A1h, w1, b1, x, O);
}

// Round 19
// 300.351 us; speedup vs baseline: 4.2117x; 2.0285x over previous
//
#include <hip/hip_runtime.h>
#include <hip/hip_bf16.h>
#include <hip/hip_fp16.h>

typedef __hip_bfloat16 bf16;
typedef unsigned int   u32;
typedef unsigned short u16;

#define HW 4096
#define NB 4

__device__ __forceinline__ float blo(u32 v){ return __uint_as_float(v << 16); }
__device__ __forceinline__ float bhi(u32 v){ return __uint_as_float(v & 0xffff0000u); }
__device__ __forceinline__ u32 pack2(float a, float b){
  union { bf16 h; u16 u; } ua, ub;
  ua.h = __float2bfloat16(a); ub.h = __float2bfloat16(b);
  return (u32)ua.u | ((u32)ub.u << 16);
}

// ---- transpose dw[c][K2] -> dwT[tt][256] ----
__global__ __launch_bounds__(256) void k_dwT(const float* __restrict__ dw, float* __restrict__ dwT, int K2){
  int tt = blockIdx.x;
  dwT[tt*256 + threadIdx.x] = dw[threadIdx.x*K2 + tt];
}

// ---- transpose x NCHW f32 -> xh NHWC bf16 ----
__global__ __launch_bounds__(256) void k_transpose(const float* __restrict__ x, bf16* __restrict__ xh){
  __shared__ float tile[64][65];
  int t = threadIdx.x, blk = blockIdx.x;
  int ct = blk & 3, pt = (blk >> 2) & 63, b = blk >> 8;
  int lp = t & 63, l4 = t >> 6;
  #pragma unroll
  for (int i = 0; i < 16; ++i){
    int cl = l4 + 4*i;
    tile[cl][lp] = x[((size_t)(b*256 + ct*64 + cl))*HW + pt*64 + lp];
  }
  __syncthreads();
  #pragma unroll
  for (int i = 0; i < 16; ++i){
    int pl = l4 + 4*i;
    xh[((size_t)b*HW + pt*64 + pl)*256 + ct*64 + lp] = __float2bfloat16(tile[lp][pl]);
  }
}

// ---- tiled 1x1 conv: NHWC bf16 in -> NCHW f32 out ----
// grid (512, ceil(OC/OCB)); block 256 = 64 oc-slots x 4 px-groups; 32 px/block
__global__ __launch_bounds__(256) void k_c1x1_nhwc(const bf16* __restrict__ a, const float* __restrict__ w,
                                                   const float* __restrict__ bias, float* __restrict__ out,
                                                   int OC, int OCB){
  __shared__ u32   a2[32*129];   // 32 px x 128 ch-pairs
  __shared__ float w2[50*65];    // <=50 oc x 64-ic chunk
  int t = threadIdx.x;
  int pix0 = blockIdx.x * 32;
  int oc0  = blockIdx.y * OCB;
  int ocnt = min(OCB, OC - oc0);
  const u32* a32 = (const u32*)a;
  int j = t & 127, half = t >> 7;
  #pragma unroll
  for (int ii = 0; ii < 16; ++ii){
    int i = half*16 + ii;
    a2[i*129 + j] = a32[(size_t)(pix0 + i)*128 + j];
  }
  int oc_l = t >> 2, pg = t & 3;
  float acc[8];
  float bv = (oc_l < ocnt) ? bias[oc0 + oc_l] : 0.f;
  #pragma unroll
  for (int q = 0; q < 8; ++q) acc[q] = bv;
  for (int c0 = 0; c0 < 256; c0 += 64){
    __syncthreads();
    for (int idx = t; idx < ocnt*64; idx += 256){
      int o = idx >> 6, jj = idx & 63;
      w2[o*65 + jj] = w[(size_t)(oc0 + o)*256 + c0 + jj];
    }
    __syncthreads();
    if (oc_l < ocnt){
      #pragma unroll 8
      for (int jj2 = 0; jj2 < 32; ++jj2){
        float wlo = w2[oc_l*65 + 2*jj2], whi = w2[oc_l*65 + 2*jj2 + 1];
        #pragma unroll
        for (int q = 0; q < 8; ++q){
          u32 av = a2[(pg*8 + q)*129 + (c0 >> 1) + jj2];
          acc[q] += blo(av)*wlo + bhi(av)*whi;
        }
      }
    }
  }
  if (oc_l < ocnt){
    int b = pix0 >> 12, pr = (pix0 & 4095) + pg*8;
    float* po = out + (size_t)(b*OC + oc0 + oc_l)*HW + pr;
    float4 v0 = make_float4(acc[0], acc[1], acc[2], acc[3]);
    float4 v1 = make_float4(acc[4], acc[5], acc[6], acc[7]);
    ((float4*)po)[0] = v0;
    ((float4*)po)[1] = v1;
  }
}

// ---- depthwise 3x3 pad1, f32 -> f32 ----
__global__ __launch_bounds__(256) void k_dw3(const float* __restrict__ in, const float* __restrict__ w,
                                             const float* __restrict__ bias, float* __restrict__ out, int OC){
  int bo = blockIdx.x;
  int oc = bo % OC;
  int p  = blockIdx.y*256 + threadIdx.x;
  int y = p >> 6, x = p & 63;
  const float* ib = in + (size_t)bo*HW;
  float acc = bias[oc];
  #pragma unroll
  for (int dy = 0; dy < 3; ++dy){
    int yy = y + dy - 1;
    if (yy < 0 || yy > 63) continue;
    #pragma unroll
    for (int dx = 0; dx < 3; ++dx){
      int xx = x + dx - 1;
      if (xx < 0 || xx > 63) continue;
      acc += ib[yy*64 + xx] * w[oc*9 + dy*3 + dx];
    }
  }
  out[(size_t)bo*HW + p] = acc;
}

// ---- precompute bilinear tables: 4 f16 slot-weights + u16 clamped base ----
template<int K, int PAD, int DIL>
__global__ __launch_bounds__(256) void k_precomp(const float* __restrict__ off,
                                                 uint2* __restrict__ pw, u16* __restrict__ pa){
  constexpr int K2 = K*K;
  int bt = blockIdx.x;                 // b*K2 + tt
  int b  = bt / K2, tt = bt % K2;
  int p  = blockIdx.y*256 + threadIdx.x;
  int yi = p >> 6, xi = p & 63;
  const float* ob = off + ((size_t)(b*2*K2) + 2*tt)*HW + p;
  float dy = ob[0];
  float dx = ob[HW];
  float py = (float)(yi + (tt/K)*DIL - PAD) + dy;
  float px = (float)(xi + (tt%K)*DIL - PAD) + dx;
  float fy = floorf(py), fx = floorf(px);
  float ty = py - fy, tx = px - fx;
  int iy = (int)fy, ix = (int)fx;
  int sy = min(max(iy, 0), 62);
  int sx = min(max(ix, 0), 62);
  float wy0 = (sy   == iy) ? (1.f-ty) : ((sy   == iy+1) ? ty : 0.f);
  float wy1 = (sy+1 == iy) ? (1.f-ty) : ((sy+1 == iy+1) ? ty : 0.f);
  float wx0 = (sx   == ix) ? (1.f-tx) : ((sx   == ix+1) ? tx : 0.f);
  float wx1 = (sx+1 == ix) ? (1.f-tx) : ((sx+1 == ix+1) ? tx : 0.f);
  u32 lo = (u32)__half_as_ushort(__float2half(wy0*wx0))
         | ((u32)__half_as_ushort(__float2half(wy0*wx1)) << 16);
  u32 hi = (u32)__half_as_ushort(__float2half(wy1*wx0))
         | ((u32)__half_as_ushort(__float2half(wy1*wx1)) << 16);
  size_t idx = (size_t)bt*HW + p;
  pw[idx] = make_uint2(lo, hi);
  pa[idx] = (u16)(sy*64 + sx);
}

// ---- NHWC deformable depthwise: thread = (pixel, channel-group of 8) ----
template<int K2>
__global__ __launch_bounds__(256) void k_deform_nhwc(
    const bf16* __restrict__ xh, const uint2* __restrict__ pw, const u16* __restrict__ pa,
    const float* __restrict__ dwT, bf16* __restrict__ oh){
  __shared__ uint2 lw[K2][8];
  __shared__ u16   la[K2][8];
  int t  = threadIdx.x;
  int cg = t & 31;
  int pl = t >> 5;
  int blk = blockIdx.x;        // b*512 + ptile
  int b   = blk >> 9;
  int p0  = (blk & 511) * 8;
  for (int e = t; e < 8*K2; e += 256){
    int tt = e >> 3, pxl = e & 7;
    size_t gi = ((size_t)(b*K2 + tt))*HW + p0 + pxl;
    lw[tt][pxl] = pw[gi];
    la[tt][pxl] = pa[gi];
  }
  __syncthreads();
  const bf16* xb = xh + (size_t)b*HW*256;
  float acc[8];
  #pragma unroll
  for (int j = 0; j < 8; ++j) acc[j] = 0.f;
  for (int tt = 0; tt < K2; ++tt){
    uint2 wv = lw[tt][pl];
    int   a  = la[tt][pl];
    float W00 = __half2float(__ushort_as_half((u16)(wv.x & 0xffffu)));
    float W01 = __half2float(__ushort_as_half((u16)(wv.x >> 16)));
    float W10 = __half2float(__ushort_as_half((u16)(wv.y & 0xffffu)));
    float W11 = __half2float(__ushort_as_half((u16)(wv.y >> 16)));
    const bf16* base = xb + (size_t)a*256 + cg*8;
    uint4 r00 = *(const uint4*)(base);
    uint4 r01 = *(const uint4*)(base + 256);
    uint4 r10 = *(const uint4*)(base + 64*256);
    uint4 r11 = *(const uint4*)(base + 65*256);
    float4 dwa = *(const float4*)(dwT + tt*256 + cg*8);
    float4 dwb = *(const float4*)(dwT + tt*256 + cg*8 + 4);
    const u32 q00[4] = {r00.x, r00.y, r00.z, r00.w};
    const u32 q01[4] = {r01.x, r01.y, r01.z, r01.w};
    const u32 q10[4] = {r10.x, r10.y, r10.z, r10.w};
    const u32 q11[4] = {r11.x, r11.y, r11.z, r11.w};
    const float dwv[8] = {dwa.x, dwa.y, dwa.z, dwa.w, dwb.x, dwb.y, dwb.z, dwb.w};
    #pragma unroll
    for (int q = 0; q < 4; ++q){
      float sl = W00*blo(q00[q]) + W01*blo(q01[q]) + W10*blo(q10[q]) + W11*blo(q11[q]);
      float sh = W00*bhi(q00[q]) + W01*bhi(q01[q]) + W10*bhi(q10[q]) + W11*bhi(q11[q]);
      acc[2*q]   += dwv[2*q]   * sl;
      acc[2*q+1] += dwv[2*q+1] * sh;
    }
  }
  size_t op = ((size_t)b*HW + p0 + pl)*256 + cg*8;
  uint4 ov;
  ov.x = pack2(acc[0], acc[1]); ov.y = pack2(acc[2], acc[3]);
  ov.z = pack2(acc[4], acc[5]); ov.w = pack2(acc[6], acc[7]);
  *(uint4*)(oh + op) = ov;
}

// ---- final 1x1 + x-multiply: attn NHWC bf16 in, out NCHW f32 ----
__global__ __launch_bounds__(256) void k_final(const bf16* __restrict__ attnh, const float* __restrict__ w1,
                                               const float* __restrict__ b1, const float* __restrict__ x,
                                               float* __restrict__ out){
  __shared__ float at[256][33];
  __shared__ float wt[256][17];
  int t   = threadIdx.x;
  int blk = blockIdx.x;
  int b   = blk >> 7;
  int p0  = (blk & 127) * 32;
  for (int i = 0; i < 32; ++i)
    at[t][i] = __bfloat162float(attnh[((size_t)b*HW + p0 + i)*256 + t]);
  float acc[32];
  float bv = b1[t];
  for (int i = 0; i < 32; ++i) acc[i] = bv;
  for (int c0 = 0; c0 < 256; c0 += 16){
    __syncthreads();
    for (int k = 0; k < 16; ++k){
      int idx = k*256 + t;
      wt[idx >> 4][idx & 15] = w1[(idx >> 4)*256 + c0 + (idx & 15)];
    }
    __syncthreads();
    for (int j = 0; j < 16; ++j){
      float wv = wt[t][j];
      const float* ar = &at[c0 + j][0];
      for (int i = 0; i < 32; ++i)
        acc[i] += wv * ar[i];
    }
  }
  size_t gi = ((size_t)(b*256 + t))*HW + p0;
  for (int i = 0; i < 32; ++i)
    out[gi + i] = acc[i] * x[gi + i];
}

extern "C" void kernel_launch(void* const* d_in, const int* in_sizes, int n_in,
                              void* d_out, int out_size, void* d_ws, size_t ws_size,
                              hipStream_t stream){
  const float* x   = (const float*)d_in[0];
  const float* aw0 = (const float*)d_in[1];
  const float* ab0 = (const float*)d_in[2];
  const float* ow0 = (const float*)d_in[3];
  const float* ob0 = (const float*)d_in[4];
  const float* dw0 = (const float*)d_in[5];
  const float* aw1 = (const float*)d_in[6];
  const float* ab1 = (const float*)d_in[7];
  const float* ow1 = (const float*)d_in[8];
  const float* ob1 = (const float*)d_in[9];
  const float* dw1 = (const float*)d_in[10];
  const float* w1  = (const float*)d_in[11];
  const float* b1  = (const float*)d_in[12];
  float* O = (float*)d_out;

  // ws regions (proven ws >= 29,622,272):
  //  R0 @0   (8M): xh NHWC bf16 -> XC1 f32 (6.42M) -> P1w (6.42M)
  //  R1 @8M  (8M): XC0(3.28M)+OF0(3.28M) -> OF1 f32 (6.42M) -> A1h NHWC bf16 (8M)
  //  R2 @16M (8M): A0h NHWC bf16 (8M)
  //  R3 @24M (4.3M): P0w(3.28M)+P0a(0.82M) -> P1a(1.6M) | dwT0+dwT1 @ +4.096M
  const size_t MB8 = 8388608;
  char* ws = (char*)d_ws;
  bf16*  xh   = (bf16*) (ws);
  float* XC1  = (float*)(ws);
  uint2* P1w  = (uint2*)(ws);
  float* XC0  = (float*)(ws + MB8);
  float* OF0  = (float*)(ws + MB8 + 3276800);
  float* OF1  = (float*)(ws + MB8);
  bf16*  A1h  = (bf16*) (ws + MB8);
  bf16*  A0h  = (bf16*) (ws + 2*MB8);
  uint2* P0w  = (uint2*)(ws + 3*MB8);
  u16*   P0a  = (u16*)  (ws + 3*MB8 + 3276800);
  u16*   P1a  = (u16*)  (ws + 3*MB8);
  float* dwT0 = (float*)(ws + 3*MB8 + 4096000);
  float* dwT1 = (float*)(ws + 3*MB8 + 4198400);

  // prep
  k_dwT<<<25, 256, 0, stream>>>(dw0, dwT0, 25);
  k_dwT<<<49, 256, 0, stream>>>(dw1, dwT1, 49);
  k_transpose<<<1024, 256, 0, stream>>>(x, xh);
  // block 0 (K=5, pad 2, dil 1)   [grid 512 = 16384 px / 32 px per block]
  k_c1x1_nhwc<<<dim3(512, 1), 256, 0, stream>>>(xh, aw0, ab0, XC0, 50, 50);
  k_dw3<<<dim3(NB*50, 16), 256, 0, stream>>>(XC0, ow0, ob0, OF0, 50);
  k_precomp<5,2,1><<<dim3(NB*25, 16), 256, 0, stream>>>(OF0, P0w, P0a);
  k_deform_nhwc<25><<<NB*512, 256, 0, stream>>>(xh, P0w, P0a, dwT0, A0h);
  // block 1 (K=7, pad 9, dil 3)  [xh dead after deform0]
  k_c1x1_nhwc<<<dim3(512, 2), 256, 0, stream>>>(A0h, aw1, ab1, XC1, 98, 49);
  k_dw3<<<dim3(NB*98, 16), 256, 0, stream>>>(XC1, ow1, ob1, OF1, 98);
  k_precomp<7,9,3><<<dim3(NB*49, 16), 256, 0, stream>>>(OF1, P1w, P1a);   // P0 dead
  k_deform_nhwc<49><<<NB*512, 256, 0, stream>>>(A0h, P1w, P1a, dwT1, A1h); // OF1 dead -> A1h@R1
  // final 1x1 + x-multiply -> d_out
  k_final<<<NB*128, 256, 0, stream>>>(A1h, w1, b1, x, O);
}

// Round 20
// 294.424 us; speedup vs baseline: 4.2965x; 1.0201x over previous
//
#include <hip/hip_runtime.h>
#include <hip/hip_bf16.h>
#include <hip/hip_fp16.h>

typedef __hip_bfloat16 bf16;
typedef unsigned int   u32;
typedef unsigned short u16;

#define HW 4096
#define NB 4

__device__ __forceinline__ float blo(u32 v){ return __uint_as_float(v << 16); }
__device__ __forceinline__ float bhi(u32 v){ return __uint_as_float(v & 0xffff0000u); }
__device__ __forceinline__ u32 pack2(float a, float b){
  union { bf16 h; u16 u; } ua, ub;
  ua.h = __float2bfloat16(a); ub.h = __float2bfloat16(b);
  return (u32)ua.u | ((u32)ub.u << 16);
}

// ---- transpose dw[c][K2] -> dwT[tt][256] ----
__global__ __launch_bounds__(256) void k_dwT(const float* __restrict__ dw, float* __restrict__ dwT, int K2){
  int tt = blockIdx.x;
  dwT[tt*256 + threadIdx.x] = dw[threadIdx.x*K2 + tt];
}

// ---- transpose x NCHW f32 -> xh NHWC bf16 ----
__global__ __launch_bounds__(256) void k_transpose(const float* __restrict__ x, bf16* __restrict__ xh){
  __shared__ float tile[64][65];
  int t = threadIdx.x, blk = blockIdx.x;
  int ct = blk & 3, pt = (blk >> 2) & 63, b = blk >> 8;
  int lp = t & 63, l4 = t >> 6;
  #pragma unroll
  for (int i = 0; i < 16; ++i){
    int cl = l4 + 4*i;
    tile[cl][lp] = x[((size_t)(b*256 + ct*64 + cl))*HW + pt*64 + lp];
  }
  __syncthreads();
  #pragma unroll
  for (int i = 0; i < 16; ++i){
    int pl = l4 + 4*i;
    xh[((size_t)b*HW + pt*64 + pl)*256 + ct*64 + lp] = __float2bfloat16(tile[lp][pl]);
  }
}

// ---- tiled 1x1 conv: NHWC bf16 in -> NCHW f32 out ----
// grid (512, ceil(OC/OCB)); block 256 = 64 oc-slots x 4 px-groups; 32 px/block
__global__ __launch_bounds__(256) void k_c1x1_nhwc(const bf16* __restrict__ a, const float* __restrict__ w,
                                                   const float* __restrict__ bias, float* __restrict__ out,
                                                   int OC, int OCB){
  __shared__ u32   a2[32*129];
  __shared__ float w2[50*65];
  int t = threadIdx.x;
  int pix0 = blockIdx.x * 32;
  int oc0  = blockIdx.y * OCB;
  int ocnt = min(OCB, OC - oc0);
  const u32* a32 = (const u32*)a;
  int j = t & 127, half = t >> 7;
  #pragma unroll
  for (int ii = 0; ii < 16; ++ii){
    int i = half*16 + ii;
    a2[i*129 + j] = a32[(size_t)(pix0 + i)*128 + j];
  }
  int oc_l = t >> 2, pg = t & 3;
  float acc[8];
  float bv = (oc_l < ocnt) ? bias[oc0 + oc_l] : 0.f;
  #pragma unroll
  for (int q = 0; q < 8; ++q) acc[q] = bv;
  for (int c0 = 0; c0 < 256; c0 += 64){
    __syncthreads();
    for (int idx = t; idx < ocnt*64; idx += 256){
      int o = idx >> 6, jj = idx & 63;
      w2[o*65 + jj] = w[(size_t)(oc0 + o)*256 + c0 + jj];
    }
    __syncthreads();
    if (oc_l < ocnt){
      #pragma unroll 8
      for (int jj2 = 0; jj2 < 32; ++jj2){
        float wlo = w2[oc_l*65 + 2*jj2], whi = w2[oc_l*65 + 2*jj2 + 1];
        #pragma unroll
        for (int q = 0; q < 8; ++q){
          u32 av = a2[(pg*8 + q)*129 + (c0 >> 1) + jj2];
          acc[q] += blo(av)*wlo + bhi(av)*whi;
        }
      }
    }
  }
  if (oc_l < ocnt){
    int b = pix0 >> 12, pr = (pix0 & 4095) + pg*8;
    float* po = out + (size_t)(b*OC + oc0 + oc_l)*HW + pr;
    ((float4*)po)[0] = make_float4(acc[0], acc[1], acc[2], acc[3]);
    ((float4*)po)[1] = make_float4(acc[4], acc[5], acc[6], acc[7]);
  }
}

// ---- depthwise 3x3 pad1, f32 -> f32 ----
__global__ __launch_bounds__(256) void k_dw3(const float* __restrict__ in, const float* __restrict__ w,
                                             const float* __restrict__ bias, float* __restrict__ out, int OC){
  int bo = blockIdx.x;
  int oc = bo % OC;
  int p  = blockIdx.y*256 + threadIdx.x;
  int y = p >> 6, x = p & 63;
  const float* ib = in + (size_t)bo*HW;
  float acc = bias[oc];
  #pragma unroll
  for (int dy = 0; dy < 3; ++dy){
    int yy = y + dy - 1;
    if (yy < 0 || yy > 63) continue;
    #pragma unroll
    for (int dx = 0; dx < 3; ++dx){
      int xx = x + dx - 1;
      if (xx < 0 || xx > 63) continue;
      acc += ib[yy*64 + xx] * w[oc*9 + dy*3 + dx];
    }
  }
  out[(size_t)bo*HW + p] = acc;
}

// ---- fused deformable depthwise: precomp-in-LDS + NHWC gathers ----
// block: 256 thr = 8 px x 32 channel-groups; grid NB*512
template<int K, int PAD, int DIL, int UNR>
__global__ __launch_bounds__(256) void k_deform_f(
    const bf16* __restrict__ xh, const float* __restrict__ off,
    const float* __restrict__ dwT, bf16* __restrict__ oh){
  constexpr int K2 = K*K;
  __shared__ uint2 lw[K2][8];
  __shared__ u16   la[K2][8];
  int t  = threadIdx.x;
  int cg = t & 31;
  int pl = t >> 5;
  int blk = blockIdx.x;        // b*512 + ptile
  int b   = blk >> 9;
  int p0  = (blk & 511) * 8;
  // fused precomp: 8*K2 table entries from offsets
  for (int e = t; e < 8*K2; e += 256){
    int tt = e >> 3, pxl = e & 7;
    int p  = p0 + pxl;
    int yi = p >> 6, xi = p & 63;
    const float* ob = off + ((size_t)(b*2*K2) + 2*tt)*HW + p;
    float dy = ob[0];
    float dx = ob[HW];
    float py = (float)(yi + (tt/K)*DIL - PAD) + dy;
    float px = (float)(xi + (tt%K)*DIL - PAD) + dx;
    float fy = floorf(py), fx = floorf(px);
    float ty = py - fy, tx = px - fx;
    int iy = (int)fy, ix = (int)fx;
    int sy = min(max(iy, 0), 62);
    int sx = min(max(ix, 0), 62);
    float wy0 = (sy   == iy) ? (1.f-ty) : ((sy   == iy+1) ? ty : 0.f);
    float wy1 = (sy+1 == iy) ? (1.f-ty) : ((sy+1 == iy+1) ? ty : 0.f);
    float wx0 = (sx   == ix) ? (1.f-tx) : ((sx   == ix+1) ? tx : 0.f);
    float wx1 = (sx+1 == ix) ? (1.f-tx) : ((sx+1 == ix+1) ? tx : 0.f);
    u32 lo = (u32)__half_as_ushort(__float2half(wy0*wx0))
           | ((u32)__half_as_ushort(__float2half(wy0*wx1)) << 16);
    u32 hi = (u32)__half_as_ushort(__float2half(wy1*wx0))
           | ((u32)__half_as_ushort(__float2half(wy1*wx1)) << 16);
    lw[tt][pxl] = make_uint2(lo, hi);
    la[tt][pxl] = (u16)(sy*64 + sx);
  }
  __syncthreads();
  const bf16* xb = xh + (size_t)b*HW*256;
  float acc[8];
  #pragma unroll
  for (int j = 0; j < 8; ++j) acc[j] = 0.f;
  #pragma unroll UNR
  for (int tt = 0; tt < K2; ++tt){
    uint2 wv = lw[tt][pl];
    int   a  = la[tt][pl];
    float W00 = __half2float(__ushort_as_half((u16)(wv.x & 0xffffu)));
    float W01 = __half2float(__ushort_as_half((u16)(wv.x >> 16)));
    float W10 = __half2float(__ushort_as_half((u16)(wv.y & 0xffffu)));
    float W11 = __half2float(__ushort_as_half((u16)(wv.y >> 16)));
    const bf16* base = xb + (size_t)a*256 + cg*8;
    uint4 r00 = *(const uint4*)(base);
    uint4 r01 = *(const uint4*)(base + 256);
    uint4 r10 = *(const uint4*)(base + 64*256);
    uint4 r11 = *(const uint4*)(base + 65*256);
    float4 dwa = *(const float4*)(dwT + tt*256 + cg*8);
    float4 dwb = *(const float4*)(dwT + tt*256 + cg*8 + 4);
    const u32 q00[4] = {r00.x, r00.y, r00.z, r00.w};
    const u32 q01[4] = {r01.x, r01.y, r01.z, r01.w};
    const u32 q10[4] = {r10.x, r10.y, r10.z, r10.w};
    const u32 q11[4] = {r11.x, r11.y, r11.z, r11.w};
    const float dwv[8] = {dwa.x, dwa.y, dwa.z, dwa.w, dwb.x, dwb.y, dwb.z, dwb.w};
    #pragma unroll
    for (int q = 0; q < 4; ++q){
      float sl = W00*blo(q00[q]) + W01*blo(q01[q]) + W10*blo(q10[q]) + W11*blo(q11[q]);
      float sh = W00*bhi(q00[q]) + W01*bhi(q01[q]) + W10*bhi(q10[q]) + W11*bhi(q11[q]);
      acc[2*q]   += dwv[2*q]   * sl;
      acc[2*q+1] += dwv[2*q+1] * sh;
    }
  }
  size_t op = ((size_t)b*HW + p0 + pl)*256 + cg*8;
  uint4 ov;
  ov.x = pack2(acc[0], acc[1]); ov.y = pack2(acc[2], acc[3]);
  ov.z = pack2(acc[4], acc[5]); ov.w = pack2(acc[6], acc[7]);
  *(uint4*)(oh + op) = ov;
}

// ---- final 1x1 + x-multiply: attn NHWC bf16 in, out NCHW f32 ----
__global__ __launch_bounds__(256) void k_final(const bf16* __restrict__ attnh, const float* __restrict__ w1,
                                               const float* __restrict__ b1, const float* __restrict__ x,
                                               float* __restrict__ out){
  __shared__ float at[256][33];
  __shared__ float wt[256][17];
  int t   = threadIdx.x;
  int blk = blockIdx.x;
  int b   = blk >> 7;
  int p0  = (blk & 127) * 32;
  for (int i = 0; i < 32; ++i)
    at[t][i] = __bfloat162float(attnh[((size_t)b*HW + p0 + i)*256 + t]);
  float acc[32];
  float bv = b1[t];
  for (int i = 0; i < 32; ++i) acc[i] = bv;
  for (int c0 = 0; c0 < 256; c0 += 16){
    __syncthreads();
    for (int k = 0; k < 16; ++k){
      int idx = k*256 + t;
      wt[idx >> 4][idx & 15] = w1[(idx >> 4)*256 + c0 + (idx & 15)];
    }
    __syncthreads();
    for (int j = 0; j < 16; ++j){
      float wv = wt[t][j];
      const float* ar = &at[c0 + j][0];
      for (int i = 0; i < 32; ++i)
        acc[i] += wv * ar[i];
    }
  }
  size_t gi = ((size_t)(b*256 + t))*HW + p0;
  for (int i = 0; i < 32; ++i)
    out[gi + i] = acc[i] * x[gi + i];
}

extern "C" void kernel_launch(void* const* d_in, const int* in_sizes, int n_in,
                              void* d_out, int out_size, void* d_ws, size_t ws_size,
                              hipStream_t stream){
  const float* x   = (const float*)d_in[0];
  const float* aw0 = (const float*)d_in[1];
  const float* ab0 = (const float*)d_in[2];
  const float* ow0 = (const float*)d_in[3];
  const float* ob0 = (const float*)d_in[4];
  const float* dw0 = (const float*)d_in[5];
  const float* aw1 = (const float*)d_in[6];
  const float* ab1 = (const float*)d_in[7];
  const float* ow1 = (const float*)d_in[8];
  const float* ob1 = (const float*)d_in[9];
  const float* dw1 = (const float*)d_in[10];
  const float* w1  = (const float*)d_in[11];
  const float* b1  = (const float*)d_in[12];
  float* O = (float*)d_out;

  // ws regions (no precomp tables anymore; peak ~24.1 MB <= proven 29.6 MB):
  //  R0 @0   (8M): xh NHWC bf16 -> XC1 f32 (6.42M) -> A1h NHWC bf16 (8M)
  //  R1 @8M  (8M): XC0(3.28M)+OF0(3.28M) -> OF1 f32 (6.42M)
  //  R2 @16M (8M): A0h NHWC bf16
  //  R3 @24M     : dwT0 (25.6K) + dwT1 (50.2K)
  const size_t MB8 = 8388608;
  char* ws = (char*)d_ws;
  bf16*  xh   = (bf16*) (ws);
  float* XC1  = (float*)(ws);
  bf16*  A1h  = (bf16*) (ws);
  float* XC0  = (float*)(ws + MB8);
  float* OF0  = (float*)(ws + MB8 + 3276800);
  float* OF1  = (float*)(ws + MB8);
  bf16*  A0h  = (bf16*) (ws + 2*MB8);
  float* dwT0 = (float*)(ws + 3*MB8);
  float* dwT1 = (float*)(ws + 3*MB8 + 102400);

  // prep
  k_dwT<<<25, 256, 0, stream>>>(dw0, dwT0, 25);
  k_dwT<<<49, 256, 0, stream>>>(dw1, dwT1, 49);
  k_transpose<<<1024, 256, 0, stream>>>(x, xh);
  // block 0 (K=5, pad 2, dil 1)
  k_c1x1_nhwc<<<dim3(512, 1), 256, 0, stream>>>(xh, aw0, ab0, XC0, 50, 50);
  k_dw3<<<dim3(NB*50, 16), 256, 0, stream>>>(XC0, ow0, ob0, OF0, 50);
  k_deform_f<5,2,1,5><<<NB*512, 256, 0, stream>>>(xh, OF0, dwT0, A0h);
  // block 1 (K=7, pad 9, dil 3)  [xh dead -> XC1@R0; XC0/OF0 dead -> OF1@R1]
  k_c1x1_nhwc<<<dim3(512, 2), 256, 0, stream>>>(A0h, aw1, ab1, XC1, 98, 49);
  k_dw3<<<dim3(NB*98, 16), 256, 0, stream>>>(XC1, ow1, ob1, OF1, 98);
  k_deform_f<7,9,3,7><<<NB*512, 256, 0, stream>>>(A0h, OF1, dwT1, A1h);  // XC1 dead -> A1h@R0
  // final 1x1 + x-multiply -> d_out
  k_final<<<NB*128, 256, 0, stream>>>(A1h, w1, b1, x, O);
}